// Round 10
// baseline (12562.827 us; speedup 1.0000x reference)
//
#include <hip/hip_runtime.h>
#include <hip/hip_fp16.h>

// 2-layer LSTM B=256 T=512 I=32 H=256.
// 16 groups x 16 batches; per group TWO 1024-thread wgs (16 waves each):
//   wg0 = L0 recurrence entirely on one CU (Whh0 in VGPRs, h0 in LDS A-frags);
//   wg1 = L1 recurrence on another CU (Wih1+Whh1 in VGPRs, h1 in LDS).
// Cross-CU traffic: ONLY the h0 stream, via a 16-slot MALL ring (sc0 sc1,
// fp16 LSB lap tag, fire-and-forget stores, prefetch+tag-spin consume) --
// the ring's 16-step slack buffers the MALL latency out of the critical path.
// wg0 throttles on a coarse progress dword when 16 ahead (rare, paced by wg1).
// 1 barrier/step in each wg. No cross-CU sync inside either recurrence.

#define TT 512
#define HH 256

typedef _Float16 f16x8 __attribute__((ext_vector_type(8)));
typedef float    f32x4 __attribute__((ext_vector_type(4)));
typedef unsigned u32x4 __attribute__((ext_vector_type(4)));

__device__ __forceinline__ f16x8 cvt8(const float* p) {
  const float4 a = *(const float4*)p;
  const float4 b = *(const float4*)(p + 4);
  f16x8 r;
  r[0]=(_Float16)a.x; r[1]=(_Float16)a.y; r[2]=(_Float16)a.z; r[3]=(_Float16)a.w;
  r[4]=(_Float16)b.x; r[5]=(_Float16)b.y; r[6]=(_Float16)b.z; r[7]=(_Float16)b.w;
  return r;
}
__device__ __forceinline__ float sigm(float x){ return 1.f/(1.f + __expf(-x)); }
__device__ __forceinline__ float tanh_(float x){ return 1.f - 2.f/(1.f + __expf(2.f*x)); }

// ---- MALL-coherent (L2-bypass) primitives ----
__device__ __forceinline__ u32x4 ld16_sv(unsigned voff, const void* base) {
  u32x4 r;
  asm volatile("global_load_dwordx4 %0, %1, %2 sc0 sc1"
               : "=v"(r) : "v"(voff), "s"(base) : "memory");
  return r;
}
__device__ __forceinline__ void st2_sv(unsigned voff, unsigned v, void* base) {
  asm volatile("global_store_short %0, %1, %2 sc0 sc1"
               :: "v"(voff), "v"(v), "s"(base) : "memory");
}
__device__ __forceinline__ void stp(void* p, unsigned v) {
  asm volatile("global_store_dword %0, %1, off sc0 sc1"
               :: "v"(p), "v"(v) : "memory");
}
__device__ __forceinline__ unsigned ldp(const void* p) {
  unsigned r;
  asm volatile("global_load_dword %0, %1, off sc0 sc1\n\ts_waitcnt vmcnt(0)"
               : "=v"(r) : "v"(p) : "memory");
  return r;
}
__device__ __forceinline__ void wvm0() {
  asm volatile("s_waitcnt vmcnt(0)" ::: "memory");
  __builtin_amdgcn_sched_barrier(0);
}
__device__ __forceinline__ void barrier_lds() {   // lgkm drain only
  __builtin_amdgcn_sched_barrier(0);
  asm volatile("s_waitcnt lgkmcnt(0)" ::: "memory");
  __builtin_amdgcn_s_barrier();
  __builtin_amdgcn_sched_barrier(0);
}

__global__ void init_ws(uint4* p, int n) {
  int i = blockIdx.x * blockDim.x + threadIdx.x;
  if (i >= n) return;
  // ring slots: fp16 LSB tag = 1 (never matches first lap's tag 0); prog = 0
  p[i] = (i < 131072) ? make_uint4(0x00010001u,0x00010001u,0x00010001u,0x00010001u)
                      : make_uint4(0u,0u,0u,0u);
}

__global__ __launch_bounds__(1024) void lstm_v10(
    const float* __restrict__ M,
    const float* __restrict__ Wih0, const float* __restrict__ Whh0,
    const float* __restrict__ bih0, const float* __restrict__ bhh0,
    const float* __restrict__ Wih1, const float* __restrict__ Whh1,
    const float* __restrict__ bih1, const float* __restrict__ bhh1,
    float* __restrict__ out, char* __restrict__ ws)
{
  __shared__ __align__(16) char ldsH[16384];  // h[t] A-frags, 2 parities x 8KB
  __shared__ __align__(16) char ldsS[16384];  // wg1: staged h0[t], 2 parities

  const int tid  = threadIdx.x, lane = tid & 63, wv = tid >> 6;   // wave 0..15
  const int g    = blockIdx.x >> 1;
  const bool isL1 = blockIdx.x & 1;
  const int col16 = lane & 15, ko8 = (lane >> 4) << 3;
  const int unit = wv * 16 + col16;           // this wave's 16 units
  const int brow = (lane >> 4) << 2;          // C-frag batch row base

  char* ring = ws + ((size_t)g << 17);        // 16 slots x 8KB per group
  int*  prog = (int*)(ws + (1 << 21) + (g << 8));

  // ---- register-resident weights: 4 gates x 16 units per wave ----
  f16x8 WA[4][8], WB[4][8], WI[4];
  float bias[4];
  #pragma unroll
  for (int q = 0; q < 4; ++q) {
    const int row = q * HH + unit;
    if (!isL1) {
      #pragma unroll
      for (int kt = 0; kt < 8; ++kt)
        WA[q][kt] = cvt8(Whh0 + (size_t)row * HH + kt * 32 + ko8);
      WI[q]   = cvt8(Wih0 + (size_t)row * 32 + ko8);
      bias[q] = bih0[row] + bhh0[row];
    } else {
      #pragma unroll
      for (int kt = 0; kt < 8; ++kt) {
        WA[q][kt] = cvt8(Wih1 + (size_t)row * HH + kt * 32 + ko8);
        WB[q][kt] = cvt8(Whh1 + (size_t)row * HH + kt * 32 + ko8);
      }
      bias[q] = bih1[row] + bhh1[row];
    }
  }

  // h scatter dest (elementwise -> A-frag layout), unit-constant part
  const unsigned ubase = ((unsigned)(unit >> 5) << 10)
                       | ((unsigned)((unit >> 3) & 3) << 8)
                       | ((unsigned)(unit & 7) << 1);

  // L0: M A-frag pointers (plain cached loads)
  const float* mp = M + (size_t)(g * 16 + col16) * TT * 32 + ko8;
  float4 m0 = {0,0,0,0}, m1 = {0,0,0,0};
  if (!isL1) { m0 = *(const float4*)mp; m1 = *(const float4*)(mp + 4); }

  // L1 stager: chunk c -> ring offset & LDS offset c*16; initial prefetch
  const unsigned moff = ((unsigned)(tid & 15) << 9) | ((unsigned)(tid >> 6) << 6)
                      | ((unsigned)((tid >> 4) & 3) << 4);
  u32x4 pf;
  if (isL1 && tid < 512) pf = ld16_sv(moff, ring);

  // zero h[-1] frags (both parities)
  *(u32x4*)(ldsH + tid * 16) = (u32x4){0u,0u,0u,0u};
  float cst[4] = {0.f, 0.f, 0.f, 0.f};
  barrier_lds();

  for (int t = 0; t < TT; ++t) {
    const int par = t & 1, ppar = par ^ 1;

    if (!isL1) {
      // ================= L0: whole recurrence on this CU =================
      f32x4 acc[4];
      f16x8 am;
      am[0]=(_Float16)m0.x; am[1]=(_Float16)m0.y; am[2]=(_Float16)m0.z; am[3]=(_Float16)m0.w;
      am[4]=(_Float16)m1.x; am[5]=(_Float16)m1.y; am[6]=(_Float16)m1.z; am[7]=(_Float16)m1.w;
      #pragma unroll
      for (int q = 0; q < 4; ++q) {
        acc[q] = (f32x4){bias[q], bias[q], bias[q], bias[q]};
        acc[q] = __builtin_amdgcn_mfma_f32_16x16x32_f16(am, WI[q], acc[q], 0, 0, 0);
      }
      #pragma unroll
      for (int kt = 0; kt < 8; ++kt) {
        const f16x8 A = *(const f16x8*)(ldsH + ppar * 8192 + kt * 1024 + lane * 16);
        #pragma unroll
        for (int q = 0; q < 4; ++q)
          acc[q] = __builtin_amdgcn_mfma_f32_16x16x32_f16(A, WA[q][kt], acc[q], 0, 0, 0);
      }
      if (t + 1 < TT) {                       // prefetch M[t+1]
        m0 = *(const float4*)(mp + (t + 1) * 32);
        m1 = *(const float4*)(mp + (t + 1) * 32 + 4);
      }
      // ring-full throttle (16-slot slack; only active when 16 ahead of wg1)
      if (t >= 16) { while ((int)ldp(prog) < t - 15) {} }

      char* slot = ring + (size_t)(t & 15) * 8192;
      const unsigned wt = (unsigned)((t >> 4) & 1);    // lap tag
      #pragma unroll
      for (int r = 0; r < 4; ++r) {
        const float iv = sigm(acc[0][r]), fv = sigm(acc[1][r]);
        const float gv = tanh_(acc[2][r]), ov = sigm(acc[3][r]);
        cst[r] = fv * cst[r] + iv * gv;
        const float h = ov * tanh_(cst[r]);
        unsigned short hb = __builtin_bit_cast(unsigned short, (_Float16)h);
        hb = (unsigned short)((hb & 0xFFFEu) | wt);
        st2_sv((unsigned)((brow + r) * 512 + unit * 2), (unsigned)hb, slot);
        *(unsigned short*)(ldsH + par * 8192 + ubase + ((unsigned)(brow + r) << 4)) = hb;
      }
      barrier_lds();                          // h0[t] frags ready for t+1
    } else {
      // ================= L1: whole recurrence on this CU =================
      // stage h0[t] (prefetched; tag-spin if not yet produced)
      if (tid < 512) {
        const char* slot = ring + (size_t)(t & 15) * 8192;
        const unsigned pat = ((unsigned)((t >> 4) & 1)) * 0x00010001u;
        wvm0();
        for (;;) {
          const u32x4 d = (pf ^ pat) & 0x00010001u;
          if (__all((d[0] | d[1] | d[2] | d[3]) == 0)) break;
          pf = ld16_sv(moff, slot);
          wvm0();
        }
        *(u32x4*)(ldsS + par * 8192 + tid * 16) = pf;
      }
      barrier_lds();                          // staged + h1[t-1] frags ready
      if (tid == 0) stp(prog, (unsigned)(t + 1));
      if (tid < 512 && t + 1 < TT)            // prefetch next slot
        pf = ld16_sv(moff, ring + (size_t)((t + 1) & 15) * 8192);

      f32x4 acc[4];
      #pragma unroll
      for (int q = 0; q < 4; ++q)
        acc[q] = (f32x4){bias[q], bias[q], bias[q], bias[q]};
      #pragma unroll
      for (int kt = 0; kt < 8; ++kt) {        // Wih1 * h0[t]
        const f16x8 A = *(const f16x8*)(ldsS + par * 8192 + kt * 1024 + lane * 16);
        #pragma unroll
        for (int q = 0; q < 4; ++q)
          acc[q] = __builtin_amdgcn_mfma_f32_16x16x32_f16(A, WA[q][kt], acc[q], 0, 0, 0);
      }
      #pragma unroll
      for (int kt = 0; kt < 8; ++kt) {        // Whh1 * h1[t-1]
        const f16x8 A = *(const f16x8*)(ldsH + ppar * 8192 + kt * 1024 + lane * 16);
        #pragma unroll
        for (int q = 0; q < 4; ++q)
          acc[q] = __builtin_amdgcn_mfma_f32_16x16x32_f16(A, WB[q][kt], acc[q], 0, 0, 0);
      }
      #pragma unroll
      for (int r = 0; r < 4; ++r) {
        const float iv = sigm(acc[0][r]), fv = sigm(acc[1][r]);
        const float gv = tanh_(acc[2][r]), ov = sigm(acc[3][r]);
        cst[r] = fv * cst[r] + iv * gv;
        const float h = ov * tanh_(cst[r]);
        if (t < TT - 1) {
          const unsigned short hb = __builtin_bit_cast(unsigned short, (_Float16)h);
          *(unsigned short*)(ldsH + par * 8192 + ubase + ((unsigned)(brow + r) << 4)) = hb;
        } else {
          out[(size_t)(g * 16 + brow + r) * HH + unit] = h;   // final h1, fp32
        }
      }
      // no trailing barrier needed: next iteration's barrier orders ldsH writes
    }
  }
}

extern "C" void kernel_launch(void* const* d_in, const int* in_sizes, int n_in,
                              void* d_out, int out_size, void* d_ws, size_t ws_size,
                              hipStream_t stream) {
  (void)in_sizes; (void)n_in; (void)out_size;
  if (ws_size < 2101248) return;   // 2MB rings + prog (ws >= 4.7MB proven in r6)

  const float* M    = (const float*)d_in[0];
  const float* Wih0 = (const float*)d_in[1];
  const float* Whh0 = (const float*)d_in[2];
  const float* bih0 = (const float*)d_in[3];
  const float* bhh0 = (const float*)d_in[4];
  const float* Wih1 = (const float*)d_in[5];
  const float* Whh1 = (const float*)d_in[6];
  const float* bih1 = (const float*)d_in[7];
  const float* bhh1 = (const float*)d_in[8];

  const int n16 = 131328;          // 2MB rings + 4KB prog, in uint4s
  init_ws<<<(n16 + 255) / 256, 256, 0, stream>>>((uint4*)d_ws, n16);
  lstm_v10<<<32, 1024, 0, stream>>>(M, Wih0, Whh0, bih0, bhh0,
                                    Wih1, Whh1, bih1, bhh1,
                                    (float*)d_out, (char*)d_ws);
}

// Round 12
// 1486.093 us; speedup vs baseline: 8.4536x; 8.4536x over previous
//
#include <hip/hip_runtime.h>
#include <hip/hip_fp16.h>

// 2-layer LSTM B=256 T=512 I=32 H=256.
// 16 groups x 16 batches x 6 wgs (512 thr): L0a/L0b (Whh0 halves, recurrence
// pair), W1a/W1b (Wih1 halves, h0->xg1 stream, slack-buffered), L1a/L1b
// (Whh1 halves, recurrence pair + xg1 add + output).
// MALL (sc0 sc1) rings with fp16-LSB lap tags (r9/r10-proven). Primitives use
// per-lane 64-bit "off" addressing (r2-r8-proven; "s"(base) saddr form breaks
// under divergent CF -- r11 compile failure).
// 512-thr wgs => 256 VGPR cap (fixes r10 spill). LDS 48KB (fixes r6 abort).
// Fallback: r9 kernel (1580us proven) when ws too small.

#define TT 512
#define HH 256
#define GS 294912   // per-group ws: 128K h0 stream + 16K h1r + 128K xg + prog

typedef _Float16 f16x8 __attribute__((ext_vector_type(8)));
typedef float    f32x4 __attribute__((ext_vector_type(4)));
typedef unsigned u32x4 __attribute__((ext_vector_type(4)));

__device__ __forceinline__ f16x8 cvt8(const float* p) {
  const float4 a = *(const float4*)p;
  const float4 b = *(const float4*)(p + 4);
  f16x8 r;
  r[0]=(_Float16)a.x; r[1]=(_Float16)a.y; r[2]=(_Float16)a.z; r[3]=(_Float16)a.w;
  r[4]=(_Float16)b.x; r[5]=(_Float16)b.y; r[6]=(_Float16)b.z; r[7]=(_Float16)b.w;
  return r;
}
__device__ __forceinline__ float sigm(float x){ return 1.f/(1.f + __expf(-x)); }
__device__ __forceinline__ float tanh_(float x){ return 1.f - 2.f/(1.f + __expf(2.f*x)); }

// ---- MALL-coherent (L2-bypass) primitives, per-lane 64b addressing ----
__device__ __forceinline__ u32x4 ld16(const void* p) {
  u32x4 r;
  asm volatile("global_load_dwordx4 %0, %1, off sc0 sc1"
               : "=v"(r) : "v"(p) : "memory");
  return r;
}
__device__ __forceinline__ void st2(void* p, unsigned v) {
  asm volatile("global_store_short %0, %1, off sc0 sc1"
               :: "v"(p), "v"(v) : "memory");
}
__device__ __forceinline__ void stp(void* p, unsigned v) {
  asm volatile("global_store_dword %0, %1, off sc0 sc1"
               :: "v"(p), "v"(v) : "memory");
}
__device__ __forceinline__ unsigned ldp(const void* p) {
  unsigned r;
  asm volatile("global_load_dword %0, %1, off sc0 sc1\n\ts_waitcnt vmcnt(0)"
               : "=v"(r) : "v"(p) : "memory");
  return r;
}
__device__ __forceinline__ void wvm0() {
  asm volatile("s_waitcnt vmcnt(0)" ::: "memory");
  __builtin_amdgcn_sched_barrier(0);
}
__device__ __forceinline__ void barrier_lds() {
  __builtin_amdgcn_sched_barrier(0);
  asm volatile("s_waitcnt lgkmcnt(0)" ::: "memory");
  __builtin_amdgcn_s_barrier();
  __builtin_amdgcn_sched_barrier(0);
}

__global__ void init_ws(uint4* p, int n) {
  int i = blockIdx.x * blockDim.x + threadIdx.x;
  if (i >= n) return;
  int rem = i % (GS / 16);
  p[i] = (rem < 17408) ? make_uint4(0x00010001u,0x00010001u,0x00010001u,0x00010001u)
                       : make_uint4(0u,0u,0u,0u);   // prog dwords = 0
}

__global__ __launch_bounds__(512) void lstm_v11(
    const float* __restrict__ M,
    const float* __restrict__ Wih0, const float* __restrict__ Whh0,
    const float* __restrict__ bih0, const float* __restrict__ bhh0,
    const float* __restrict__ Wih1, const float* __restrict__ Whh1,
    const float* __restrict__ bih1, const float* __restrict__ bhh1,
    float* __restrict__ out, char* __restrict__ ws)
{
  __shared__ __align__(16) char ldsH[16384];   // 2-parity A-frag h (L0/L1)
  __shared__ __align__(16) char ldsX[32768];   // L1: xg dbuf; W1: staged h0 dbuf

  const int tid  = threadIdx.x, lane = tid & 63, wv = tid >> 6;   // 8 waves
  const int bid  = blockIdx.x;
  const int g    = bid / 6;
  const int r6   = bid - g * 6;
  const int role = r6 >> 1;            // 0:L0 1:W1 2:L1
  const int half = r6 & 1;
  const int col16 = lane & 15, ko8 = (lane >> 4) << 3, brow = (lane >> 4) << 2;
  const int unit = half * 128 + wv * 16 + col16;

  char* base   = ws + (size_t)g * GS;
  char* stream = base;                 // 16 slots x 8KB, A-frag layout
  char* h1r    = base + 131072;        // 2 parity slots x 8KB, A-frag layout
  char* xg     = base + 147456;        // 4 slots x [2 half x 16KB]
  int*  prog   = (int*)(base + 278528);   // [0]=W1a [1]=W1b [2]=L1a [3]=L1b

  // A-frag byte position of (batch b, unit u): ubase|(b<<4)  [r10-validated]
  const unsigned ubase = ((unsigned)(unit >> 5) << 10)
                       | ((unsigned)((unit >> 3) & 3) << 8)
                       | ((unsigned)(unit & 7) << 1);
  const unsigned pb = (unsigned)(half ^ 1) * 4096;   // partner ktile region

  // ---- register-resident weights: 4 gates x 16 units (this wave) ----
  f16x8 W[4][8], WI[4];
  float bias[4] = {0.f, 0.f, 0.f, 0.f};
  {
    const float* Wsrc = (role == 0) ? Whh0 : (role == 1) ? Wih1 : Whh1;
    #pragma unroll
    for (int q = 0; q < 4; ++q) {
      const int row = q * HH + unit;
      #pragma unroll
      for (int kt = 0; kt < 8; ++kt)
        W[q][kt] = cvt8(Wsrc + (size_t)row * HH + kt * 32 + ko8);
      if (role == 0) { WI[q] = cvt8(Wih0 + (size_t)row * 32 + ko8);
                       bias[q] = bih0[row] + bhh0[row]; }
      else if (role == 1) bias[q] = bih1[row] + bhh1[row];
    }
  }

  float cst[4] = {0.f, 0.f, 0.f, 0.f};

  if (role == 0) {
    // =================== L0 pair: latency-critical recurrence ===================
    const float* mp = M + (size_t)(g * 16 + col16) * TT * 32 + ko8;
    float4 m0 = *(const float4*)mp, m1 = *(const float4*)(mp + 4);
    int lastW = 0;
    for (int t = 0; t < TT; ++t) {
      const int rpar = (t - 1) & 1;
      if (t >= 1 && tid < 256) {       // stage partner h0[t-1] half (4KB)
        const char* a = stream + (size_t)((t - 1) & 15) * 8192 + pb + tid * 16;
        const unsigned pat = (((unsigned)(t - 1) >> 4) & 1u) * 0x00010001u;
        u32x4 v = ld16(a);
        wvm0();
        for (;;) {
          const u32x4 d = (v ^ pat) & 0x00010001u;
          if (__all((d[0] | d[1] | d[2] | d[3]) == 0)) break;
          v = ld16(a);
          wvm0();
        }
        *(u32x4*)(ldsH + rpar * 8192 + pb + tid * 16) = v;
      }
      barrier_lds();
      if (t >= 16) {                   // slot overwrite throttle vs W1 pair
        while (lastW < t - 15) {
          const int a = (int)ldp(prog + 0), b = (int)ldp(prog + 1);
          lastW = a < b ? a : b;
        }
      }
      f32x4 acc[4];
      f16x8 am;
      am[0]=(_Float16)m0.x; am[1]=(_Float16)m0.y; am[2]=(_Float16)m0.z; am[3]=(_Float16)m0.w;
      am[4]=(_Float16)m1.x; am[5]=(_Float16)m1.y; am[6]=(_Float16)m1.z; am[7]=(_Float16)m1.w;
      #pragma unroll
      for (int q = 0; q < 4; ++q) {
        acc[q] = (f32x4){bias[q], bias[q], bias[q], bias[q]};
        acc[q] = __builtin_amdgcn_mfma_f32_16x16x32_f16(am, WI[q], acc[q], 0, 0, 0);
      }
      if (t >= 1) {
        #pragma unroll
        for (int kt = 0; kt < 8; ++kt) {
          const f16x8 A = *(const f16x8*)(ldsH + rpar * 8192 + kt * 1024 + lane * 16);
          #pragma unroll
          for (int q = 0; q < 4; ++q)
            acc[q] = __builtin_amdgcn_mfma_f32_16x16x32_f16(A, W[q][kt], acc[q], 0, 0, 0);
        }
      }
      if (t + 1 < TT) { m0 = *(const float4*)(mp + (t + 1) * 32);
                        m1 = *(const float4*)(mp + (t + 1) * 32 + 4); }
      char* slot = stream + (size_t)(t & 15) * 8192;
      const unsigned wt = ((unsigned)t >> 4) & 1u;
      #pragma unroll
      for (int r = 0; r < 4; ++r) {
        const float iv = sigm(acc[0][r]), fv = sigm(acc[1][r]);
        const float gv = tanh_(acc[2][r]), ov = sigm(acc[3][r]);
        cst[r] = fv * cst[r] + iv * gv;
        const float h = ov * tanh_(cst[r]);
        unsigned short hb = __builtin_bit_cast(unsigned short, (_Float16)h);
        hb = (unsigned short)((hb & 0xFFFEu) | wt);
        const unsigned fo = ubase + ((unsigned)(brow + r) << 4);
        st2(slot + fo, (unsigned)hb);                         // fire-and-forget
        *(unsigned short*)(ldsH + (t & 1) * 8192 + fo) = hb;  // own-half local
      }
    }
  } else if (role == 1) {
    // =================== W1 pair: Wih1*h0 -> xg1 stream (slack) ===================
    int lastL = 0;
    for (int t = 0; t < TT; ++t) {
      const char* a = stream + (size_t)(t & 15) * 8192 + tid * 16;
      const unsigned pat = (((unsigned)t >> 4) & 1u) * 0x00010001u;
      u32x4 v = ld16(a);                     // stage full h0[t] (8KB)
      wvm0();
      for (;;) {
        const u32x4 d = (v ^ pat) & 0x00010001u;
        if (__all((d[0] | d[1] | d[2] | d[3]) == 0)) break;
        v = ld16(a);
        wvm0();
      }
      *(u32x4*)(ldsX + (t & 1) * 8192 + tid * 16) = v;
      barrier_lds();
      if (tid == 0) stp(prog + half, (unsigned)(t + 1));
      if (t >= 4) { while (lastL < t - 3) lastL = (int)ldp(prog + 2 + half); }
      f32x4 acc[4];
      #pragma unroll
      for (int q = 0; q < 4; ++q)
        acc[q] = (f32x4){bias[q], bias[q], bias[q], bias[q]};
      #pragma unroll
      for (int kt = 0; kt < 8; ++kt) {
        const f16x8 A = *(const f16x8*)(ldsX + (t & 1) * 8192 + kt * 1024 + lane * 16);
        #pragma unroll
        for (int q = 0; q < 4; ++q)
          acc[q] = __builtin_amdgcn_mfma_f32_16x16x32_f16(A, W[q][kt], acc[q], 0, 0, 0);
      }
      char* xs = xg + (size_t)(t & 3) * 32768 + half * 16384;
      const unsigned wtx = ((unsigned)t >> 2) & 1u;
      #pragma unroll
      for (int q = 0; q < 4; ++q)
        #pragma unroll
        for (int r = 0; r < 4; ++r) {
          unsigned short hb = __builtin_bit_cast(unsigned short, (_Float16)acc[q][r]);
          hb = (unsigned short)((hb & 0xFFFEu) | wtx);
          const unsigned off = (unsigned)(brow + r) * 1024
                             + (unsigned)(q * 128 + wv * 16 + col16) * 2;
          st2(xs + off, (unsigned)hb);
        }
    }
  } else {
    // =================== L1 pair: recurrence + xg1 add + output ===================
    for (int t = 0; t < TT; ++t) {
      const int rpar = (t - 1) & 1;
      const char* sx = xg + (size_t)(t & 3) * 32768 + half * 16384;
      const unsigned patX = (((unsigned)t >> 2) & 1u) * 0x00010001u;
      const char* sa = h1r + (size_t)rpar * 8192 + pb + tid * 16;
      const unsigned patA = (((unsigned)(t - 1) >> 1) & 1u) * 0x00010001u;
      const bool hasA = (t >= 1) && (tid < 256);
      u32x4 x0 = ld16(sx + tid * 32), x1 = ld16(sx + tid * 32 + 16), va;
      if (hasA) va = ld16(sa);
      wvm0();
      for (;;) {
        u32x4 d = ((x0 ^ patX) | (x1 ^ patX)) & 0x00010001u;
        unsigned bad = d[0] | d[1] | d[2] | d[3];
        if (hasA) { const u32x4 e = (va ^ patA) & 0x00010001u;
                    bad |= e[0] | e[1] | e[2] | e[3]; }
        if (__all(bad == 0)) break;
        x0 = ld16(sx + tid * 32); x1 = ld16(sx + tid * 32 + 16);
        if (hasA) va = ld16(sa);
        wvm0();
      }
      *(u32x4*)(ldsX + (t & 1) * 16384 + tid * 32)      = x0;
      *(u32x4*)(ldsX + (t & 1) * 16384 + tid * 32 + 16) = x1;
      if (hasA) *(u32x4*)(ldsH + rpar * 8192 + pb + tid * 16) = va;
      barrier_lds();
      if (tid == 0) stp(prog + 2 + half, (unsigned)(t + 1));
      f32x4 acc[4];
      #pragma unroll
      for (int q = 0; q < 4; ++q) acc[q] = (f32x4){0.f, 0.f, 0.f, 0.f};
      if (t >= 1) {
        #pragma unroll
        for (int kt = 0; kt < 8; ++kt) {
          const f16x8 A = *(const f16x8*)(ldsH + rpar * 8192 + kt * 1024 + lane * 16);
          #pragma unroll
          for (int q = 0; q < 4; ++q)
            acc[q] = __builtin_amdgcn_mfma_f32_16x16x32_f16(A, W[q][kt], acc[q], 0, 0, 0);
        }
      }
      const char* xl = ldsX + (t & 1) * 16384;
      #pragma unroll
      for (int q = 0; q < 4; ++q)
        #pragma unroll
        for (int r = 0; r < 4; ++r) {
          const unsigned short xv = *(const unsigned short*)
            (xl + (brow + r) * 1024 + (q * 128 + wv * 16 + col16) * 2);
          acc[q][r] += (float)__builtin_bit_cast(_Float16, xv);
        }
      char* d1 = h1r + (size_t)(t & 1) * 8192;
      const unsigned wt = ((unsigned)t >> 1) & 1u;
      #pragma unroll
      for (int r = 0; r < 4; ++r) {
        const float iv = sigm(acc[0][r]), fv = sigm(acc[1][r]);
        const float gv = tanh_(acc[2][r]), ov = sigm(acc[3][r]);
        cst[r] = fv * cst[r] + iv * gv;
        const float h = ov * tanh_(cst[r]);
        if (t < TT - 1) {
          unsigned short hb = __builtin_bit_cast(unsigned short, (_Float16)h);
          hb = (unsigned short)((hb & 0xFFFEu) | wt);
          const unsigned fo = ubase + ((unsigned)(brow + r) << 4);
          st2(d1 + fo, (unsigned)hb);
          *(unsigned short*)(ldsH + (t & 1) * 8192 + fo) = hb;
        } else {
          out[(size_t)(g * 16 + brow + r) * HH + unit] = h;
        }
      }
    }
  }
}

// ================= fallback: round-9 kernel (1580us proven) =================
__global__ void fb_init(uint4* p, int n) {
  int i = blockIdx.x * blockDim.x + threadIdx.x;
  if (i < n) p[i] = make_uint4(0x00010001u,0x00010001u,0x00010001u,0x00010001u);
}
__device__ __forceinline__ unsigned fb_tg(int t){ return ((unsigned)(t + 4) >> 1) & 1u; }

__global__ __launch_bounds__(512) void lstm_v9(
    const float* __restrict__ M,
    const float* __restrict__ Wih0, const float* __restrict__ Whh0,
    const float* __restrict__ bih0, const float* __restrict__ bhh0,
    const float* __restrict__ Wih1, const float* __restrict__ Whh1,
    const float* __restrict__ bih1, const float* __restrict__ bhh1,
    float* __restrict__ out, char* __restrict__ ws)
{
  __shared__ __align__(16) char  ldsA[16384];
  __shared__ __align__(16) f32x4 xch[8][64];
  const int tid  = threadIdx.x, lane = tid & 63, wv = tid >> 6;
  const int g = blockIdx.x & 7, w = blockIdx.x >> 3;
  const int hf = wv & 1, role = wv >> 1;
  const int col16 = lane & 15, ko8 = (lane >> 4) << 3;
  const int unit = w * 16 + col16;
  #define H0R(slot) (ws + (((g << 1) | (slot)) << 14))
  #define H1R(slot) (ws + 262144 + (((g << 1) | (slot)) << 14))
  f16x8 W0[4][8], WI[4];
  float bias[4] = {0.f, 0.f, 0.f, 0.f};
  if (role == 0) {
    #pragma unroll
    for (int q = 0; q < 4; ++q) {
      const int row = q * HH + unit;
      #pragma unroll
      for (int kt = 0; kt < 8; ++kt) W0[q][kt] = cvt8(Whh0 + (size_t)row*HH + kt*32 + ko8);
      WI[q] = cvt8(Wih0 + (size_t)row*32 + ko8); bias[q] = bih0[row] + bhh0[row];
    }
  } else if (role == 1) {
    #pragma unroll
    for (int q = 0; q < 4; ++q) {
      const int row = q * HH + unit;
      #pragma unroll
      for (int kt = 0; kt < 8; ++kt) W0[q][kt] = cvt8(Wih1 + (size_t)row*HH + kt*32 + ko8);
      bias[q] = bih1[row] + bhh1[row];
    }
  } else if (role == 2) {
    #pragma unroll
    for (int q = 0; q < 4; ++q) {
      const int row = q * HH + unit;
      #pragma unroll
      for (int kt = 0; kt < 8; ++kt) W0[q][kt] = cvt8(Whh1 + (size_t)row*HH + kt*32 + ko8);
    }
  }
  const int sl = tid & 63, skt = (tid >> 6) & 7;
  const unsigned moff0 = (unsigned)((sl & 15) * 512 + skt * 64 + (sl >> 4) * 16);
  const unsigned moff1 = moff0 + 16 * 512;
  const unsigned lo    = (unsigned)(skt * 1024 + sl * 16);
  const unsigned hoff = (((unsigned)(hf*16 + col16)) << 9) | ((unsigned)(lane >> 4) << 4);
  unsigned soff[4];
  #pragma unroll
  for (int r = 0; r < 4; ++r)
    soff[r] = (((unsigned)(hf*16 + ((lane>>4)<<2) + r)) << 9) | ((unsigned)unit << 1);
  const float* mp = M + (size_t)(g*32 + hf*16 + col16) * TT * 32 + ko8;
  float4 m0 = {0,0,0,0}, m1 = {0,0,0,0};
  if (role == 0) { m0 = *(const float4*)mp; m1 = *(const float4*)(mp + 4); }
  float cst[4] = {0.f, 0.f, 0.f, 0.f};
  for (int p = 0; p <= TT; ++p) {
    if (p >= 1) {
      const char* s = H0R((p - 1) & 1);
      const unsigned pat = fb_tg(p - 1) * 0x00010001u;
      u32x4 v0 = ld16(s + moff0), v1 = ld16(s + moff1);
      wvm0();
      for (;;) {
        const u32x4 d = ((v0 ^ pat) | (v1 ^ pat)) & 0x00010001u;
        if (__all((d[0] | d[1] | d[2] | d[3]) == 0)) break;
        v0 = ld16(s + moff0); v1 = ld16(s + moff1); wvm0();
      }
      *(u32x4*)(ldsA + lo) = v0; *(u32x4*)(ldsA + 8192 + lo) = v1;
    }
    barrier_lds();
    f32x4 acc[4];
    if (role == 0 && p < TT) {
      f16x8 am;
      am[0]=(_Float16)m0.x; am[1]=(_Float16)m0.y; am[2]=(_Float16)m0.z; am[3]=(_Float16)m0.w;
      am[4]=(_Float16)m1.x; am[5]=(_Float16)m1.y; am[6]=(_Float16)m1.z; am[7]=(_Float16)m1.w;
      #pragma unroll
      for (int q = 0; q < 4; ++q) {
        acc[q] = (f32x4){bias[q], bias[q], bias[q], bias[q]};
        acc[q] = __builtin_amdgcn_mfma_f32_16x16x32_f16(am, WI[q], acc[q], 0, 0, 0);
      }
      if (p >= 1) {
        #pragma unroll
        for (int kt = 0; kt < 8; ++kt) {
          const f16x8 A = *(const f16x8*)(ldsA + hf*8192 + kt*1024 + lane*16);
          #pragma unroll
          for (int q = 0; q < 4; ++q)
            acc[q] = __builtin_amdgcn_mfma_f32_16x16x32_f16(A, W0[q][kt], acc[q], 0, 0, 0);
        }
      }
      char* d = H0R(p & 1);
      const unsigned wt = fb_tg(p);
      #pragma unroll
      for (int r = 0; r < 4; ++r) {
        const float iv = sigm(acc[0][r]), fv = sigm(acc[1][r]);
        const float gv = tanh_(acc[2][r]), ov = sigm(acc[3][r]);
        cst[r] = fv * cst[r] + iv * gv;
        const float h = ov * tanh_(cst[r]);
        unsigned short hb = __builtin_bit_cast(unsigned short, (_Float16)h);
        hb = (unsigned short)((hb & 0xFFFEu) | wt);
        st2(d + soff[r], (unsigned)hb);
      }
      if (p + 1 < TT) { m0 = *(const float4*)(mp + (p+1)*32); m1 = *(const float4*)(mp + (p+1)*32 + 4); }
    } else if (role == 1 && p >= 1) {
      #pragma unroll
      for (int q = 0; q < 4; ++q) acc[q] = (f32x4){bias[q], bias[q], bias[q], bias[q]};
      #pragma unroll
      for (int kt = 0; kt < 8; ++kt) {
        const f16x8 A = *(const f16x8*)(ldsA + hf*8192 + kt*1024 + lane*16);
        #pragma unroll
        for (int q = 0; q < 4; ++q)
          acc[q] = __builtin_amdgcn_mfma_f32_16x16x32_f16(A, W0[q][kt], acc[q], 0, 0, 0);
      }
    } else if (role == 2 && p >= 2) {
      const char* s = H1R(p & 1);
      const unsigned pat = fb_tg(p - 2) * 0x00010001u;
      u32x4 hb[8];
      #pragma unroll
      for (int k = 0; k < 8; ++k) hb[k] = ld16(s + hoff + k*64);
      wvm0();
      for (;;) {
        unsigned bad = 0;
        #pragma unroll
        for (int k = 0; k < 8; ++k) {
          const u32x4 d = (hb[k] ^ pat) & 0x00010001u;
          bad |= d[0] | d[1] | d[2] | d[3];
        }
        if (__all(bad == 0)) break;
        #pragma unroll
        for (int k = 0; k < 8; ++k) hb[k] = ld16(s + hoff + k*64);
        wvm0();
      }
      #pragma unroll
      for (int q = 0; q < 4; ++q) acc[q] = (f32x4){0.f, 0.f, 0.f, 0.f};
      #pragma unroll
      for (int kt = 0; kt < 8; ++kt) {
        const f16x8 A = __builtin_bit_cast(f16x8, hb[kt]);
        #pragma unroll
        for (int q = 0; q < 4; ++q)
          acc[q] = __builtin_amdgcn_mfma_f32_16x16x32_f16(A, W0[q][kt], acc[q], 0, 0, 0);
      }
      #pragma unroll
      for (int q = 0; q < 4; ++q) xch[hf*4 + q][lane] = acc[q];
    }
    barrier_lds();
    if (role == 1 && p >= 1) {
      if (p >= 2) {
        #pragma unroll
        for (int q = 0; q < 4; ++q) acc[q] = acc[q] + xch[hf*4 + q][lane];
      }
      if (p < TT) {
        char* d = H1R((p - 1) & 1);
        const unsigned wt = fb_tg(p - 1);
        #pragma unroll
        for (int r = 0; r < 4; ++r) {
          const float iv = sigm(acc[0][r]), fv = sigm(acc[1][r]);
          const float gv = tanh_(acc[2][r]), ov = sigm(acc[3][r]);
          cst[r] = fv * cst[r] + iv * gv;
          const float h = ov * tanh_(cst[r]);
          unsigned short hb = __builtin_bit_cast(unsigned short, (_Float16)h);
          hb = (unsigned short)((hb & 0xFFFEu) | wt);
          st2(d + soff[r], (unsigned)hb);
        }
      } else {
        #pragma unroll
        for (int r = 0; r < 4; ++r) {
          const float iv = sigm(acc[0][r]), fv = sigm(acc[1][r]);
          const float gv = tanh_(acc[2][r]), ov = sigm(acc[3][r]);
          cst[r] = fv * cst[r] + iv * gv;
          const float h = ov * tanh_(cst[r]);
          const int b = hf*16 + ((lane>>4)<<2) + r;
          out[(size_t)(g*32 + b) * HH + (w*16 + col16)] = h;
        }
      }
    }
  }
  #undef H0R
  #undef H1R
}

extern "C" void kernel_launch(void* const* d_in, const int* in_sizes, int n_in,
                              void* d_out, int out_size, void* d_ws, size_t ws_size,
                              hipStream_t stream) {
  (void)in_sizes; (void)n_in; (void)out_size;
  const float* M    = (const float*)d_in[0];
  const float* Wih0 = (const float*)d_in[1];
  const float* Whh0 = (const float*)d_in[2];
  const float* bih0 = (const float*)d_in[3];
  const float* bhh0 = (const float*)d_in[4];
  const float* Wih1 = (const float*)d_in[5];
  const float* Whh1 = (const float*)d_in[6];
  const float* bih1 = (const float*)d_in[7];
  const float* bhh1 = (const float*)d_in[8];

  if (ws_size >= (size_t)16 * GS) {
    const int n16 = 16 * (GS / 16);
    init_ws<<<(n16 + 255) / 256, 256, 0, stream>>>((uint4*)d_ws, n16);
    lstm_v11<<<96, 512, 0, stream>>>(M, Wih0, Whh0, bih0, bhh0,
                                     Wih1, Whh1, bih1, bhh1,
                                     (float*)d_out, (char*)d_ws);
  } else {
    if (ws_size < 524288) return;
    fb_init<<<128, 256, 0, stream>>>((uint4*)d_ws, 32768);
    lstm_v9<<<128, 512, 0, stream>>>(M, Wih0, Whh0, bih0, bhh0,
                                     Wih1, Whh1, bih1, bhh1,
                                     (float*)d_out, (char*)d_ws);
  }
}